// Round 1
// baseline (2350.123 us; speedup 1.0000x reference)
//
#include <hip/hip_runtime.h>
#include <math.h>

#define NB 4096   // batch
#define NS 64     // seq
#define NF 8      // feat
#define ND 64     // d_model
#define NL 4096   // NS*ND
#define NK 16     // top-k

// ---------------- init accumulators ----------------
__global__ void init_acc_kernel(double* acc) {
    if (threadIdx.x < 8) acc[threadIdx.x] = 0.0;
}

// ---------------- embed: x_re = x @ W_emb + b_emb ----------------
__global__ __launch_bounds__(256) void embed_kernel(
    const float* __restrict__ x, const float* __restrict__ Wemb,
    const float* __restrict__ bemb, float* __restrict__ xre)
{
    __shared__ float sW[NF * ND];   // [f][d], 512
    __shared__ float sb[ND];
    __shared__ float sx[NS * NF];   // one batch row, 512
    const int t = threadIdx.x, b = blockIdx.x;
    sW[t] = Wemb[t]; sW[t + 256] = Wemb[t + 256];
    if (t < ND) sb[t] = bemb[t];
    sx[t] = x[(size_t)b * (NS * NF) + t];
    sx[t + 256] = x[(size_t)b * (NS * NF) + t + 256];
    __syncthreads();
    float* orow = xre + (size_t)b * NL;
    #pragma unroll
    for (int i = 0; i < NL / 256; ++i) {
        const int idx = t + i * 256;
        const int s = idx >> 6, d = idx & 63;
        float acc = sb[d];
        #pragma unroll
        for (int f = 0; f < NF; ++f) acc += sx[s * NF + f] * sW[f * ND + d];
        orow[idx] = acc;
    }
}

// ---------------- attn = (x_re @ x_re^T) / 64, diag = -inf ----------------
#define BM 64
#define BN 64
#define BK 32

__global__ __launch_bounds__(256) void attn_gemm_kernel(
    const float* __restrict__ A, float* __restrict__ C)
{
    __shared__ float sA[BK][BM];   // transposed: [k][row]
    __shared__ float sB[BK][BN];
    const int t = threadIdx.x;
    const int it = blockIdx.x & 63, jt = blockIdx.x >> 6;
    const int i0 = it * BM, j0 = jt * BN;
    const int tr = t >> 4, tc = t & 15;      // 16x16 threads, 4x4 microtile
    const int lr = t >> 3, lk = t & 7;       // loader: row 0..31, k-vec 0..7
    float acc[4][4] = {};
    const float* Ap = A + (size_t)(i0 + lr) * NL + lk * 4;
    const float* Bp = A + (size_t)(j0 + lr) * NL + lk * 4;

    for (int k0 = 0; k0 < NL; k0 += BK) {
        const float4 a0 = *(const float4*)(Ap + k0);
        const float4 a1 = *(const float4*)(Ap + (size_t)32 * NL + k0);
        const float4 b0 = *(const float4*)(Bp + k0);
        const float4 b1 = *(const float4*)(Bp + (size_t)32 * NL + k0);
        __syncthreads();   // previous tile fully consumed
        const int kb = lk * 4;
        sA[kb+0][lr] = a0.x; sA[kb+1][lr] = a0.y; sA[kb+2][lr] = a0.z; sA[kb+3][lr] = a0.w;
        sA[kb+0][lr+32] = a1.x; sA[kb+1][lr+32] = a1.y; sA[kb+2][lr+32] = a1.z; sA[kb+3][lr+32] = a1.w;
        sB[kb+0][lr] = b0.x; sB[kb+1][lr] = b0.y; sB[kb+2][lr] = b0.z; sB[kb+3][lr] = b0.w;
        sB[kb+0][lr+32] = b1.x; sB[kb+1][lr+32] = b1.y; sB[kb+2][lr+32] = b1.z; sB[kb+3][lr+32] = b1.w;
        __syncthreads();
        #pragma unroll
        for (int kk = 0; kk < BK; ++kk) {
            const float4 av = *(const float4*)&sA[kk][tr * 4];
            const float4 bv = *(const float4*)&sB[kk][tc * 4];
            const float* ap = (const float*)&av;
            const float* bp = (const float*)&bv;
            #pragma unroll
            for (int a2 = 0; a2 < 4; ++a2)
                #pragma unroll
                for (int b2 = 0; b2 < 4; ++b2)
                    acc[a2][b2] += ap[a2] * bp[b2];
        }
    }

    const float scale = 1.0f / 64.0f;
    #pragma unroll
    for (int a2 = 0; a2 < 4; ++a2) {
        const int i = i0 + tr * 4 + a2;
        const int j = j0 + tc * 4;
        float4 v;
        v.x = acc[a2][0] * scale; v.y = acc[a2][1] * scale;
        v.z = acc[a2][2] * scale; v.w = acc[a2][3] * scale;
        const int dd = i - j;
        if (dd >= 0 && dd < 4) ((float*)&v)[dd] = -INFINITY;
        *(float4*)&C[(size_t)i * NB + j] = v;
    }
}

// ---------------- proj: out = x_re @ W_proj + b_proj ----------------
// (softmax row-sums are exactly 1, so x_rec == x_re)
__global__ __launch_bounds__(256) void proj_kernel(
    const float* __restrict__ xre, const float* __restrict__ Wp,
    const float* __restrict__ bp, float* __restrict__ out)
{
    __shared__ float sW[ND * NF];   // [d][f], 512
    __shared__ float sb[NF];
    __shared__ float sx[NL];        // 16 KB
    const int t = threadIdx.x, b = blockIdx.x;
    sW[t] = Wp[t]; sW[t + 256] = Wp[t + 256];
    if (t < NF) sb[t] = bp[t];
    const float4* xr4 = (const float4*)(xre + (size_t)b * NL);
    float4* sx4 = (float4*)sx;
    #pragma unroll
    for (int i = 0; i < NL / 4 / 256; ++i) sx4[t + i * 256] = xr4[t + i * 256];
    __syncthreads();
    #pragma unroll
    for (int i = 0; i < (NS * NF) / 256; ++i) {
        const int e = t + i * 256;
        const int s = e >> 3, f = e & 7;
        float acc = sb[f];
        #pragma unroll
        for (int d = 0; d < ND; ++d) acc += sx[s * ND + d] * sW[d * NF + f];
        out[(size_t)b * (NS * NF) + e] = acc;
    }
}

// ---------------- top-k per row (descending, stable = lowest index on ties) ----------------
__global__ __launch_bounds__(256) void topk_kernel(
    const float* __restrict__ attn, int* __restrict__ topidx)
{
    __shared__ float row[NB];     // 16 KB
    __shared__ float rv[256];
    __shared__ int   ri[256];
    const int b = blockIdx.x, t = threadIdx.x;
    for (int i = t; i < NB; i += 256) row[i] = attn[(size_t)b * NB + i];
    __syncthreads();
    for (int k = 0; k < NK; ++k) {
        float best = -INFINITY;
        int bi = 1 << 30;
        for (int i = t; i < NB; i += 256) {
            const float v = row[i];
            if (v > best || (v == best && i < bi)) { best = v; bi = i; }
        }
        rv[t] = best; ri[t] = bi;
        __syncthreads();
        for (int s2 = 128; s2 > 0; s2 >>= 1) {
            if (t < s2) {
                const float v2 = rv[t + s2]; const int i2 = ri[t + s2];
                if (v2 > rv[t] || (v2 == rv[t] && i2 < ri[t])) { rv[t] = v2; ri[t] = i2; }
            }
            __syncthreads();
        }
        if (t == 0) { topidx[b * NK + k] = ri[0]; row[ri[0]] = -INFINITY; }
        __syncthreads();
    }
}

// ---------------- block reduce helper ----------------
__device__ __forceinline__ float blk_reduce(float v, float* red) {
    #pragma unroll
    for (int o = 32; o > 0; o >>= 1) v += __shfl_down(v, o, 64);
    const int t = threadIdx.x;
    __syncthreads();
    if ((t & 63) == 0) red[t >> 6] = v;
    __syncthreads();
    float r = 0.f;
    if (t == 0) r = red[0] + red[1] + red[2] + red[3];
    return r;
}

// ---------------- term1: sum((proj - x)^2) ----------------
__global__ __launch_bounds__(256) void term1_kernel(
    const float* __restrict__ proj, const float* __restrict__ x, double* __restrict__ acc)
{
    const int n = NB * NS * NF;
    __shared__ float red[4];
    float s = 0.f;
    for (int i = blockIdx.x * 256 + threadIdx.x; i < n; i += gridDim.x * 256) {
        const float d = proj[i] - x[i];
        s += d * d;
    }
    const float tot = blk_reduce(s, red);
    if (threadIdx.x == 0) atomicAdd(&acc[0], (double)tot);
}

// ---------------- gathered diffs ----------------
__global__ __launch_bounds__(256) void diffs_kernel(
    const float* __restrict__ proj, const int* __restrict__ topidx, double* __restrict__ acc)
{
    __shared__ float g[NK][NS * NF];   // 32 KB
    __shared__ int sidx[NK];
    __shared__ float red[4];
    const int t = threadIdx.x, b = blockIdx.x;
    if (t < NK) sidx[t] = topidx[b * NK + t];
    __syncthreads();
    for (int q = t; q < NK * 512; q += 256) {
        const int kk = q >> 9, e = q & 511;
        g[kk][e] = proj[(size_t)sidx[kk] * 512 + e];
    }
    __syncthreads();
    float s1 = 0.f, s2 = 0.f;
    for (int q = t; q < 15 * 512; q += 256) {          // diff along K
        const int kk = q >> 9, e = q & 511;
        const float d = g[kk + 1][e] - g[kk][e];
        s1 += d * d;
    }
    for (int q = t; q < 16 * 504; q += 256) {          // diff along S
        const int kk = q / 504, e = q % 504;
        const float d = g[kk][e + 8] - g[kk][e];
        s2 += d * d;
    }
    const float t1 = blk_reduce(s1, red);
    if (threadIdx.x == 0) atomicAdd(&acc[1], (double)t1);
    __syncthreads();
    const float t2 = blk_reduce(s2, red);
    if (threadIdx.x == 0) atomicAdd(&acc[2], (double)t2);
}

// ---------------- finalize loss ----------------
__global__ void finalize_kernel(const double* __restrict__ acc, float* __restrict__ out) {
    if (threadIdx.x == 0) {
        const double loss = acc[0] / 2097152.0      // B*S*F
                          + acc[1] / 31457280.0     // B*(K-1)*S*F
                          + acc[2] / 33030144.0;    // B*K*(S-1)*F
        out[0] = (float)loss;
    }
}

extern "C" void kernel_launch(void* const* d_in, const int* in_sizes, int n_in,
                              void* d_out, int out_size, void* d_ws, size_t ws_size,
                              hipStream_t stream) {
    const float* x    = (const float*)d_in[0];
    const float* Wemb = (const float*)d_in[1];
    const float* bemb = (const float*)d_in[2];
    const float* Wp   = (const float*)d_in[3];
    const float* bp   = (const float*)d_in[4];
    float* out  = (float*)d_out;
    float* proj = out + 1;                       // x_rec_proj, B*S*F floats

    char* ws = (char*)d_ws;
    float*  xre    = (float*)ws;                              // 64 MB
    float*  attn   = (float*)(ws + ((size_t)64 << 20));       // 64 MB
    int*    topidx = (int*)  (ws + ((size_t)128 << 20));      // 256 KB
    double* acc    = (double*)(ws + ((size_t)129 << 20));     // 24 B

    init_acc_kernel<<<1, 64, 0, stream>>>(acc);
    embed_kernel<<<NB, 256, 0, stream>>>(x, Wemb, bemb, xre);
    attn_gemm_kernel<<<64 * 64, 256, 0, stream>>>(xre, attn);
    proj_kernel<<<NB, 256, 0, stream>>>(xre, Wp, bp, proj);
    topk_kernel<<<NB, 256, 0, stream>>>(attn, topidx);
    term1_kernel<<<2048, 256, 0, stream>>>(proj, x, acc);
    diffs_kernel<<<NB, 256, 0, stream>>>(proj, topidx, acc);
    finalize_kernel<<<1, 64, 0, stream>>>(acc, out);
}

// Round 2
// 656.525 us; speedup vs baseline: 3.5796x; 3.5796x over previous
//
#include <hip/hip_runtime.h>
#include <math.h>

#define NB 4096   // batch
#define NS 64     // seq
#define NF 8      // feat
#define ND 64     // d_model
#define NL 4096   // NS*ND
#define NK 16     // top-k

typedef __bf16 bf16x8 __attribute__((ext_vector_type(8)));
typedef float  f32x4  __attribute__((ext_vector_type(4)));
typedef unsigned short u16x8 __attribute__((ext_vector_type(8)));

#define GLD16(src, dst) \
  __builtin_amdgcn_global_load_lds((const __attribute__((address_space(1))) void*)(src), \
                                   (__attribute__((address_space(3))) void*)(dst), 16, 0, 0)

__device__ __forceinline__ unsigned short f2bf_rne(float f) {
    unsigned v = __float_as_uint(f);
    return (unsigned short)((v + 0x7FFFu + ((v >> 16) & 1u)) >> 16);
}
__device__ __forceinline__ float bf2f(unsigned short u) {
    return __uint_as_float(((unsigned)u) << 16);
}

// ---------------- init accumulators ----------------
__global__ void init_acc_kernel(double* acc) {
    if (threadIdx.x < 8) acc[threadIdx.x] = 0.0;
}

// ---------------- embed: x_re = x @ W_emb + b_emb; store split bf16 hi/lo ----------------
__global__ __launch_bounds__(256) void embed_kernel(
    const float* __restrict__ x, const float* __restrict__ Wemb,
    const float* __restrict__ bemb,
    unsigned short* __restrict__ Ah, unsigned short* __restrict__ Al)
{
    __shared__ float sW[NF * ND];
    __shared__ float sb[ND];
    __shared__ float sx[NS * NF];
    const int t = threadIdx.x, b = blockIdx.x;
    sW[t] = Wemb[t]; sW[t + 256] = Wemb[t + 256];
    if (t < ND) sb[t] = bemb[t];
    sx[t] = x[(size_t)b * (NS * NF) + t];
    sx[t + 256] = x[(size_t)b * (NS * NF) + t + 256];
    __syncthreads();
    const size_t rb = (size_t)b * NL;
    #pragma unroll
    for (int i = 0; i < NL / 256; ++i) {
        const int idx = t + i * 256;
        const int s = idx >> 6, d = idx & 63;
        float acc = sb[d];
        #pragma unroll
        for (int f = 0; f < NF; ++f) acc += sx[s * NF + f] * sW[f * ND + d];
        // split: acc = hi + lo (+ ~2^-17 residual)
        unsigned v = __float_as_uint(acc);
        unsigned hb = (v + 0x7FFFu + ((v >> 16) & 1u)) & 0xFFFF0000u;
        float fhi = __uint_as_float(hb);
        float flo = acc - fhi;                 // exact (Sterbenz)
        Ah[rb + idx] = (unsigned short)(hb >> 16);
        Al[rb + idx] = f2bf_rne(flo);
    }
}

// ---------------- attn = (X @ X^T)/64 via split-bf16 MFMA, lower-tri blocks ----------------
__global__ __launch_bounds__(256) void attn_gemm_kernel(
    const unsigned short* __restrict__ Ah, const unsigned short* __restrict__ Al,
    float* __restrict__ C)
{
    __shared__ __align__(16) unsigned short sAh[128 * 32];
    __shared__ __align__(16) unsigned short sAl[128 * 32];
    __shared__ __align__(16) unsigned short sBh[128 * 32];
    __shared__ __align__(16) unsigned short sBl[128 * 32];

    const int t = threadIdx.x;
    const int lane = t & 63, wid = t >> 6;
    const int wr = wid >> 1, wc = wid & 1;     // 2x2 waves, each 64x64 out

    // triangular block decode: bid -> (it, jt), jt <= it
    int bid = blockIdx.x;
    int it = (int)((sqrtf(8.0f * (float)bid + 1.0f) - 1.0f) * 0.5f);
    while ((it + 1) * (it + 2) / 2 <= bid) ++it;
    while (it * (it + 1) / 2 > bid) --it;
    const int jt = bid - it * (it + 1) / 2;
    const int i0 = it * 128, j0 = jt * 128;

    f32x4 acc[4][4];
    #pragma unroll
    for (int m = 0; m < 4; ++m)
        #pragma unroll
        for (int n = 0; n < 4; ++n) acc[m][n] = (f32x4){0.f, 0.f, 0.f, 0.f};

    const int lrow = lane & 15, lk = (lane >> 4) * 8;

    for (int k0 = 0; k0 < NL; k0 += 32) {
        __syncthreads();   // prev iter's LDS reads done
        // stage 4 tiles (128 rows x 32 cols bf16 each), linear LDS, 16B chunks
        #pragma unroll
        for (int i2 = 0; i2 < 2; ++i2) {
            const int c = t + i2 * 256;
            const int row = c >> 2, cc = c & 3;
            const size_t goA = (size_t)(i0 + row) * NL + k0 + cc * 8;
            const size_t goB = (size_t)(j0 + row) * NL + k0 + cc * 8;
            GLD16(Ah + goA, sAh + c * 8);
            GLD16(Al + goA, sAl + c * 8);
            GLD16(Ah + goB, sBh + c * 8);
            GLD16(Al + goB, sBl + c * 8);
        }
        __syncthreads();   // drains vmcnt before compute

        bf16x8 ah[4], al[4], bh[4], bl[4];
        #pragma unroll
        for (int m = 0; m < 4; ++m) {
            const int ra = (wr * 64 + m * 16 + lrow) * 32 + lk;
            const int rb2 = (wc * 64 + m * 16 + lrow) * 32 + lk;
            ah[m] = *(const bf16x8*)&sAh[ra];
            al[m] = *(const bf16x8*)&sAl[ra];
            bh[m] = *(const bf16x8*)&sBh[rb2];
            bl[m] = *(const bf16x8*)&sBl[rb2];
        }
        #pragma unroll
        for (int m = 0; m < 4; ++m)
            #pragma unroll
            for (int n = 0; n < 4; ++n) {
                acc[m][n] = __builtin_amdgcn_mfma_f32_16x16x32_bf16(ah[m], bh[n], acc[m][n], 0, 0, 0);
                acc[m][n] = __builtin_amdgcn_mfma_f32_16x16x32_bf16(ah[m], bl[n], acc[m][n], 0, 0, 0);
                acc[m][n] = __builtin_amdgcn_mfma_f32_16x16x32_bf16(al[m], bh[n], acc[m][n], 0, 0, 0);
            }
    }

    // epilogue: C/D layout col=lane&15, row=(lane>>4)*4+reg
    const float scale = 1.0f / 64.0f;
    const int diag = (it == jt);
    #pragma unroll
    for (int m = 0; m < 4; ++m)
        #pragma unroll
        for (int n = 0; n < 4; ++n)
            #pragma unroll
            for (int r = 0; r < 4; ++r) {
                const int i = i0 + wr * 64 + m * 16 + (lane >> 4) * 4 + r;
                const int j = j0 + wc * 64 + n * 16 + (lane & 15);
                float v = acc[m][n][r] * scale;
                if (i == j) v = -INFINITY;
                C[(size_t)i * NB + j] = v;
                if (!diag) C[(size_t)j * NB + i] = v;
            }
}

// ---------------- proj: out = x_re @ W_proj + b_proj (x_re = hi+lo) ----------------
__global__ __launch_bounds__(256) void proj_kernel(
    const unsigned short* __restrict__ Ah, const unsigned short* __restrict__ Al,
    const float* __restrict__ Wp, const float* __restrict__ bp, float* __restrict__ out)
{
    __shared__ float sW[ND * NF];
    __shared__ float sb[NF];
    __shared__ float sx[NL];        // 16 KB
    const int t = threadIdx.x, b = blockIdx.x;
    sW[t] = Wp[t]; sW[t + 256] = Wp[t + 256];
    if (t < NF) sb[t] = bp[t];
    const size_t rb = (size_t)b * NL;
    #pragma unroll
    for (int i = 0; i < 2; ++i) {
        const int e0 = (t + i * 256) * 8;
        const u16x8 h = *(const u16x8*)&Ah[rb + e0];
        const u16x8 l = *(const u16x8*)&Al[rb + e0];
        #pragma unroll
        for (int j = 0; j < 8; ++j) sx[e0 + j] = bf2f(h[j]) + bf2f(l[j]);
    }
    __syncthreads();
    #pragma unroll
    for (int i = 0; i < (NS * NF) / 256; ++i) {
        const int e = t + i * 256;
        const int s = e >> 3, f = e & 7;
        float acc = sb[f];
        #pragma unroll
        for (int d = 0; d < ND; ++d) acc += sx[s * ND + d] * sW[d * NF + f];
        out[(size_t)b * (NS * NF) + e] = acc;
    }
}

// ---------------- top-k per row (descending, lowest index on ties) ----------------
__global__ __launch_bounds__(256) void topk_kernel(
    const float* __restrict__ attn, int* __restrict__ topidx)
{
    __shared__ float row[NB];
    __shared__ float rv[256];
    __shared__ int   ri[256];
    const int b = blockIdx.x, t = threadIdx.x;
    for (int i = t; i < NB; i += 256) row[i] = attn[(size_t)b * NB + i];
    __syncthreads();
    for (int k = 0; k < NK; ++k) {
        float best = -INFINITY;
        int bi = 1 << 30;
        for (int i = t; i < NB; i += 256) {
            const float v = row[i];
            if (v > best || (v == best && i < bi)) { best = v; bi = i; }
        }
        rv[t] = best; ri[t] = bi;
        __syncthreads();
        for (int s2 = 128; s2 > 0; s2 >>= 1) {
            if (t < s2) {
                const float v2 = rv[t + s2]; const int i2 = ri[t + s2];
                if (v2 > rv[t] || (v2 == rv[t] && i2 < ri[t])) { rv[t] = v2; ri[t] = i2; }
            }
            __syncthreads();
        }
        if (t == 0) { topidx[b * NK + k] = ri[0]; row[ri[0]] = -INFINITY; }
        __syncthreads();
    }
}

// ---------------- block reduce helper ----------------
__device__ __forceinline__ float blk_reduce(float v, float* red) {
    #pragma unroll
    for (int o = 32; o > 0; o >>= 1) v += __shfl_down(v, o, 64);
    const int t = threadIdx.x;
    __syncthreads();
    if ((t & 63) == 0) red[t >> 6] = v;
    __syncthreads();
    float r = 0.f;
    if (t == 0) r = red[0] + red[1] + red[2] + red[3];
    return r;
}

// ---------------- term1: sum((proj - x)^2) ----------------
__global__ __launch_bounds__(256) void term1_kernel(
    const float* __restrict__ proj, const float* __restrict__ x, double* __restrict__ acc)
{
    const int n = NB * NS * NF;
    __shared__ float red[4];
    float s = 0.f;
    for (int i = blockIdx.x * 256 + threadIdx.x; i < n; i += gridDim.x * 256) {
        const float d = proj[i] - x[i];
        s += d * d;
    }
    const float tot = blk_reduce(s, red);
    if (threadIdx.x == 0) atomicAdd(&acc[0], (double)tot);
}

// ---------------- gathered diffs ----------------
__global__ __launch_bounds__(256) void diffs_kernel(
    const float* __restrict__ proj, const int* __restrict__ topidx, double* __restrict__ acc)
{
    __shared__ float g[NK][NS * NF];   // 32 KB
    __shared__ int sidx[NK];
    __shared__ float red[4];
    const int t = threadIdx.x, b = blockIdx.x;
    if (t < NK) sidx[t] = topidx[b * NK + t];
    __syncthreads();
    for (int q = t; q < NK * 512; q += 256) {
        const int kk = q >> 9, e = q & 511;
        g[kk][e] = proj[(size_t)sidx[kk] * 512 + e];
    }
    __syncthreads();
    float s1 = 0.f, s2 = 0.f;
    for (int q = t; q < 15 * 512; q += 256) {
        const int kk = q >> 9, e = q & 511;
        const float d = g[kk + 1][e] - g[kk][e];
        s1 += d * d;
    }
    for (int q = t; q < 16 * 504; q += 256) {
        const int kk = q / 504, e = q % 504;
        const float d = g[kk][e + 8] - g[kk][e];
        s2 += d * d;
    }
    const float t1 = blk_reduce(s1, red);
    if (threadIdx.x == 0) atomicAdd(&acc[1], (double)t1);
    __syncthreads();
    const float t2 = blk_reduce(s2, red);
    if (threadIdx.x == 0) atomicAdd(&acc[2], (double)t2);
}

// ---------------- finalize loss ----------------
__global__ void finalize_kernel(const double* __restrict__ acc, float* __restrict__ out) {
    if (threadIdx.x == 0) {
        const double loss = acc[0] / 2097152.0      // B*S*F
                          + acc[1] / 31457280.0     // B*(K-1)*S*F
                          + acc[2] / 33030144.0;    // B*K*(S-1)*F
        out[0] = (float)loss;
    }
}

extern "C" void kernel_launch(void* const* d_in, const int* in_sizes, int n_in,
                              void* d_out, int out_size, void* d_ws, size_t ws_size,
                              hipStream_t stream) {
    const float* x    = (const float*)d_in[0];
    const float* Wemb = (const float*)d_in[1];
    const float* bemb = (const float*)d_in[2];
    const float* Wp   = (const float*)d_in[3];
    const float* bp   = (const float*)d_in[4];
    float* out  = (float*)d_out;
    float* proj = out + 1;                       // x_rec_proj, B*S*F floats

    char* ws = (char*)d_ws;
    unsigned short* Ah = (unsigned short*)ws;                       // 32 MB
    unsigned short* Al = (unsigned short*)(ws + ((size_t)32 << 20)); // 32 MB
    float*  attn   = (float*)(ws + ((size_t)64 << 20));             // 64 MB
    int*    topidx = (int*)  (ws + ((size_t)128 << 20));            // 256 KB
    double* acc    = (double*)(ws + ((size_t)129 << 20));           // 64 B

    init_acc_kernel<<<1, 64, 0, stream>>>(acc);
    embed_kernel<<<NB, 256, 0, stream>>>(x, Wemb, bemb, Ah, Al);
    attn_gemm_kernel<<<(32 * 33) / 2, 256, 0, stream>>>(Ah, Al, attn);
    proj_kernel<<<NB, 256, 0, stream>>>(Ah, Al, Wp, bp, proj);
    topk_kernel<<<NB, 256, 0, stream>>>(attn, topidx);
    term1_kernel<<<2048, 256, 0, stream>>>(proj, x, acc);
    diffs_kernel<<<NB, 256, 0, stream>>>(proj, topidx, acc);
    finalize_kernel<<<1, 64, 0, stream>>>(acc, out);
}

// Round 3
// 609.940 us; speedup vs baseline: 3.8530x; 1.0764x over previous
//
#include <hip/hip_runtime.h>
#include <math.h>

#define NB 4096   // batch
#define NS 64     // seq
#define NF 8      // feat
#define ND 64     // d_model
#define NL 4096   // NS*ND
#define NK 16     // top-k

typedef __bf16 bf16x8 __attribute__((ext_vector_type(8)));
typedef float  f32x4  __attribute__((ext_vector_type(4)));

#define GLD16(src, dst) \
  __builtin_amdgcn_global_load_lds((const __attribute__((address_space(1))) void*)(src), \
                                   (__attribute__((address_space(3))) void*)(dst), 16, 0, 0)

__device__ __forceinline__ unsigned short f2bf_rne(float f) {
    unsigned v = __float_as_uint(f);
    return (unsigned short)((v + 0x7FFFu + ((v >> 16) & 1u)) >> 16);
}

// ---------------- init accumulators ----------------
__global__ void init_acc_kernel(double* acc) {
    if (threadIdx.x < 8) acc[threadIdx.x] = 0.0;
}

// ---------------- block reduce helper ----------------
__device__ __forceinline__ float blk_reduce(float v, float* red) {
    #pragma unroll
    for (int o = 32; o > 0; o >>= 1) v += __shfl_down(v, o, 64);
    const int t = threadIdx.x;
    __syncthreads();
    if ((t & 63) == 0) red[t >> 6] = v;
    __syncthreads();
    float r = 0.f;
    if (t == 0) r = red[0] + red[1] + red[2] + red[3];
    return r;
}

// ---------- fused: x_enc = x@Wemb+b (split-bf16 store) ; proj = x_enc@Wp+bp ; term1 ----------
__global__ __launch_bounds__(256) void embed_proj_kernel(
    const float* __restrict__ x, const float* __restrict__ Wemb,
    const float* __restrict__ bemb, const float* __restrict__ Wp,
    const float* __restrict__ bp,
    unsigned short* __restrict__ Ah, unsigned short* __restrict__ Al,
    float* __restrict__ proj, double* __restrict__ acc)
{
    __shared__ float sW[NF * ND];      // [f][d]
    __shared__ float sbe[ND];
    __shared__ float sx[NS * NF];
    __shared__ float sWp[ND * NF];     // [d][f]
    __shared__ float sbp[NF];
    __shared__ float senc[NS * 65];    // stride-65 pad (bank-conflict-free)
    __shared__ float red[4];
    const int t = threadIdx.x, b = blockIdx.x;
    sW[t] = Wemb[t]; sW[t + 256] = Wemb[t + 256];
    sWp[t] = Wp[t];  sWp[t + 256] = Wp[t + 256];
    if (t < ND) sbe[t] = bemb[t];
    if (t < NF) sbp[t] = bp[t];
    sx[t] = x[(size_t)b * 512 + t];
    sx[t + 256] = x[(size_t)b * 512 + 256 + t];
    __syncthreads();
    const size_t rb = (size_t)b * NL;
    #pragma unroll
    for (int i = 0; i < 16; ++i) {
        const int idx = t + i * 256;
        const int s = idx >> 6, d = idx & 63;
        float a = sbe[d];
        #pragma unroll
        for (int f = 0; f < NF; ++f) a += sx[s * NF + f] * sW[f * ND + d];
        senc[s * 65 + d] = a;
        unsigned v = __float_as_uint(a);
        unsigned hb = (v + 0x7FFFu + ((v >> 16) & 1u)) & 0xFFFF0000u;
        const float fhi = __uint_as_float(hb);
        Ah[rb + idx] = (unsigned short)(hb >> 16);
        Al[rb + idx] = f2bf_rne(a - fhi);
    }
    __syncthreads();
    float s1 = 0.f;
    #pragma unroll
    for (int i = 0; i < 2; ++i) {
        const int e = t + i * 256;
        const int s = e >> 3, f = e & 7;
        float a = sbp[f];
        #pragma unroll
        for (int d = 0; d < ND; ++d) a += senc[s * 65 + d] * sWp[d * NF + f];
        proj[(size_t)b * 512 + e] = a;
        const float df = a - sx[e];
        s1 += df * df;
    }
    const float tot = blk_reduce(s1, red);
    if (t == 0) atomicAdd(&acc[0], (double)tot);
}

// ------- attn = X@X^T (unscaled, no diag) split-bf16 MFMA, lower-tri, in-block split-K -------
__global__ __launch_bounds__(512) void attn_gemm_kernel(
    const unsigned short* __restrict__ Ah, const unsigned short* __restrict__ Al,
    float* __restrict__ C)
{
    // 8 staging tiles [tt][128][32] u16: tt = kw*4 + {Ah,Al,Bh,Bl}; 64 KB total
    __shared__ __align__(16) unsigned short smem[8 * 4096];

    const int t = threadIdx.x;
    const int lane = t & 63, wid = t >> 6;
    const int kw = wid >> 2, wsub = wid & 3;      // K-half, sub-wave
    const int wr = wsub >> 1, wc = wsub & 1;      // 2x2 waves -> 64x64 out each

    // triangular block decode: bid -> (it, jt), jt <= it
    int bid = blockIdx.x;
    int it = (int)((sqrtf(8.0f * (float)bid + 1.0f) - 1.0f) * 0.5f);
    while ((it + 1) * (it + 2) / 2 <= bid) ++it;
    while (it * (it + 1) / 2 > bid) --it;
    const int jt = bid - it * (it + 1) / 2;
    const int i0 = it * 128, j0 = jt * 128;

    f32x4 acc[4][4];
    #pragma unroll
    for (int m = 0; m < 4; ++m)
        #pragma unroll
        for (int n = 0; n < 4; ++n) acc[m][n] = (f32x4){0.f, 0.f, 0.f, 0.f};

    const int lrow = lane & 15, lk = (lane >> 4) * 8;
    const int srow = t >> 2, scc = (t & 3) * 8;   // staging: row, col-offset within tile
    const int aoff = (kw * 4) * 4096;             // this K-half's tile group base (u16)

    for (int k0 = 0; k0 < 2048; k0 += 32) {
        __syncthreads();   // prev iter's LDS reads done
        #pragma unroll
        for (int i2 = 0; i2 < 8; ++i2) {
            const int arr = i2 & 3, kwt = i2 >> 2;
            const int grow = (arr < 2 ? i0 : j0) + srow;
            const size_t go = (size_t)grow * NL + kwt * 2048 + k0 + scc;
            const unsigned short* src = (arr & 1) ? Al : Ah;
            GLD16(src + go, smem + (size_t)(t + i2 * 512) * 8);
        }
        __syncthreads();   // drains vmcnt before compute

        bf16x8 fah[4], fal[4], fbh[4], fbl[4];
        #pragma unroll
        for (int m = 0; m < 4; ++m) {
            const int ra = (wr * 64 + m * 16 + lrow) * 32 + lk;
            const int rb2 = (wc * 64 + m * 16 + lrow) * 32 + lk;
            fah[m] = *(const bf16x8*)&smem[aoff + ra];
            fal[m] = *(const bf16x8*)&smem[aoff + 4096 + ra];
            fbh[m] = *(const bf16x8*)&smem[aoff + 8192 + rb2];
            fbl[m] = *(const bf16x8*)&smem[aoff + 12288 + rb2];
        }
        #pragma unroll
        for (int m = 0; m < 4; ++m)
            #pragma unroll
            for (int n = 0; n < 4; ++n) {
                acc[m][n] = __builtin_amdgcn_mfma_f32_16x16x32_bf16(fah[m], fbh[n], acc[m][n], 0, 0, 0);
                acc[m][n] = __builtin_amdgcn_mfma_f32_16x16x32_bf16(fah[m], fbl[n], acc[m][n], 0, 0, 0);
                acc[m][n] = __builtin_amdgcn_mfma_f32_16x16x32_bf16(fal[m], fbh[n], acc[m][n], 0, 0, 0);
            }
    }

    // combine K-halves through LDS, then write C (+ mirror)
    __syncthreads();
    float* fsm = (float*)smem;
    if (kw == 1) {
        #pragma unroll
        for (int m = 0; m < 4; ++m)
            #pragma unroll
            for (int n = 0; n < 4; ++n)
                *(f32x4*)&fsm[((wsub * 64 + lane) * 16 + m * 4 + n) * 4] = acc[m][n];
    }
    __syncthreads();
    if (kw == 0) {
        const int diag = (it == jt);
        #pragma unroll
        for (int m = 0; m < 4; ++m)
            #pragma unroll
            for (int n = 0; n < 4; ++n) {
                const f32x4 o = *(const f32x4*)&fsm[((wsub * 64 + lane) * 16 + m * 4 + n) * 4];
                #pragma unroll
                for (int r = 0; r < 4; ++r) {
                    const int i = i0 + wr * 64 + m * 16 + (lane >> 4) * 4 + r;
                    const int j = j0 + wc * 64 + n * 16 + (lane & 15);
                    const float v = acc[m][n][r] + o[r];
                    C[(size_t)i * NB + j] = v;
                    if (!diag) C[(size_t)j * NB + i] = v;
                }
            }
    }
}

// ---------------- top-k: one wave per row, barrier-free chunk-cached argmax ----------------
__global__ __launch_bounds__(256) void topk_kernel(
    const float* __restrict__ attn, int* __restrict__ topidx)
{
    __shared__ float rows[4][NB];   // 64 KB
    const int t = threadIdx.x, lane = t & 63, w = t >> 6;
    const int b = blockIdx.x * 4 + w;
    float* srow = rows[w];
    const float4* src = (const float4*)(attn + (size_t)b * NB);
    #pragma unroll
    for (int j = 0; j < 16; ++j) {
        const int c4 = j * 64 + lane;
        *(float4*)&srow[c4 * 4] = src[c4];
    }
    __syncthreads();
    if (lane == (b & 63)) srow[b] = -INFINITY;   // mask self (owner-lane write)

    // per-lane chunk caches: lane owns elements e with e%64==lane; 4 chunks of 16
    float cv[4]; int ci[4];
    #pragma unroll
    for (int q = 0; q < 4; ++q) {
        float bv = -INFINITY; int bi = 0;
        #pragma unroll
        for (int j = 0; j < 16; ++j) {
            const int e = (q * 16 + j) * 64 + lane;
            const float v = srow[e];
            if (v > bv) { bv = v; bi = e; }
        }
        cv[q] = bv; ci[q] = bi;
    }

    for (int k = 0; k < NK; ++k) {
        float bv = cv[0]; int bi = ci[0];
        #pragma unroll
        for (int q = 1; q < 4; ++q)
            if (cv[q] > bv || (cv[q] == bv && ci[q] < bi)) { bv = cv[q]; bi = ci[q]; }
        float v = bv; int idx = bi;
        #pragma unroll
        for (int o = 32; o > 0; o >>= 1) {
            const float v2 = __shfl_xor(v, o, 64);
            const int  i2 = __shfl_xor(idx, o, 64);
            if (v2 > v || (v2 == v && i2 < idx)) { v = v2; idx = i2; }
        }
        if (lane == 0) topidx[b * NK + k] = idx;
        if ((idx & 63) == lane) {                 // owner invalidates + rescans its chunk
            srow[idx] = -INFINITY;
            const int q = idx >> 10;
            float nbv = -INFINITY; int nbi = 0;
            #pragma unroll
            for (int j = 0; j < 16; ++j) {
                const int e = (q * 16 + j) * 64 + lane;
                const float v3 = srow[e];
                if (v3 > nbv) { nbv = v3; nbi = e; }
            }
            cv[q] = nbv; ci[q] = nbi;
        }
    }
}

// ---------------- gathered diffs ----------------
__global__ __launch_bounds__(256) void diffs_kernel(
    const float* __restrict__ proj, const int* __restrict__ topidx, double* __restrict__ acc)
{
    __shared__ float g[NK][NS * NF];   // 32 KB
    __shared__ int sidx[NK];
    __shared__ float red[4];
    const int t = threadIdx.x, b = blockIdx.x;
    if (t < NK) sidx[t] = topidx[b * NK + t];
    __syncthreads();
    for (int q = t; q < NK * 512; q += 256) {
        const int kk = q >> 9, e = q & 511;
        g[kk][e] = proj[(size_t)sidx[kk] * 512 + e];
    }
    __syncthreads();
    float s1 = 0.f, s2 = 0.f;
    for (int q = t; q < 15 * 512; q += 256) {
        const int kk = q >> 9, e = q & 511;
        const float d = g[kk + 1][e] - g[kk][e];
        s1 += d * d;
    }
    for (int q = t; q < 16 * 504; q += 256) {
        const int kk = q / 504, e = q % 504;
        const float d = g[kk][e + 8] - g[kk][e];
        s2 += d * d;
    }
    const float t1 = blk_reduce(s1, red);
    if (threadIdx.x == 0) atomicAdd(&acc[1], (double)t1);
    __syncthreads();
    const float t2 = blk_reduce(s2, red);
    if (threadIdx.x == 0) atomicAdd(&acc[2], (double)t2);
}

// ---------------- finalize loss ----------------
__global__ void finalize_kernel(const double* __restrict__ acc, float* __restrict__ out) {
    if (threadIdx.x == 0) {
        const double loss = acc[0] / 2097152.0      // B*S*F
                          + acc[1] / 31457280.0     // B*(K-1)*S*F
                          + acc[2] / 33030144.0;    // B*K*(S-1)*F
        out[0] = (float)loss;
    }
}

extern "C" void kernel_launch(void* const* d_in, const int* in_sizes, int n_in,
                              void* d_out, int out_size, void* d_ws, size_t ws_size,
                              hipStream_t stream) {
    const float* x    = (const float*)d_in[0];
    const float* Wemb = (const float*)d_in[1];
    const float* bemb = (const float*)d_in[2];
    const float* Wp   = (const float*)d_in[3];
    const float* bp   = (const float*)d_in[4];
    float* out  = (float*)d_out;
    float* proj = out + 1;                       // x_rec_proj, B*S*F floats

    char* ws = (char*)d_ws;
    unsigned short* Ah = (unsigned short*)ws;                        // 32 MB
    unsigned short* Al = (unsigned short*)(ws + ((size_t)32 << 20)); // 32 MB
    float*  attn   = (float*)(ws + ((size_t)64 << 20));              // 64 MB
    int*    topidx = (int*)  (ws + ((size_t)128 << 20));             // 256 KB
    double* acc    = (double*)(ws + ((size_t)129 << 20));            // 64 B

    init_acc_kernel<<<1, 64, 0, stream>>>(acc);
    embed_proj_kernel<<<NB, 256, 0, stream>>>(x, Wemb, bemb, Wp, bp, Ah, Al, proj, acc);
    attn_gemm_kernel<<<(32 * 33) / 2, 512, 0, stream>>>(Ah, Al, attn);
    topk_kernel<<<NB / 4, 256, 0, stream>>>(attn, topidx);
    diffs_kernel<<<NB, 256, 0, stream>>>(proj, topidx, acc);
    finalize_kernel<<<1, 64, 0, stream>>>(acc, out);
}

// Round 4
// 369.542 us; speedup vs baseline: 6.3595x; 1.6505x over previous
//
#include <hip/hip_runtime.h>
#include <math.h>

#define NB 4096   // batch
#define NS 64     // seq
#define NF 8      // feat
#define ND 64     // d_model
#define NL 4096   // NS*ND
#define NK 16     // top-k

typedef _Float16 half8 __attribute__((ext_vector_type(8)));
typedef float    f32x4 __attribute__((ext_vector_type(4)));

#define GLD16(src, dst) \
  __builtin_amdgcn_global_load_lds((const __attribute__((address_space(1))) void*)(src), \
                                   (__attribute__((address_space(3))) void*)(dst), 16, 0, 0)

// ---------------- init accumulators ----------------
__global__ void init_acc_kernel(double* acc) {
    if (threadIdx.x < 8) acc[threadIdx.x] = 0.0;
}

// ---------------- block reduce helper ----------------
__device__ __forceinline__ float blk_reduce(float v, float* red) {
    #pragma unroll
    for (int o = 32; o > 0; o >>= 1) v += __shfl_down(v, o, 64);
    const int t = threadIdx.x;
    __syncthreads();
    if ((t & 63) == 0) red[t >> 6] = v;
    __syncthreads();
    float r = 0.f;
    if (t == 0) r = red[0] + red[1] + red[2] + red[3];
    return r;
}

// ---- fused: x_enc = x@Wemb+b (fp16 store) ; proj = x_enc@Wp+bp ; term1 ----
__global__ __launch_bounds__(256) void embed_proj_kernel(
    const float* __restrict__ x, const float* __restrict__ Wemb,
    const float* __restrict__ bemb, const float* __restrict__ Wp,
    const float* __restrict__ bp,
    _Float16* __restrict__ Af, float* __restrict__ proj, double* __restrict__ acc)
{
    __shared__ float sW[NF * ND];      // [f][d]
    __shared__ float sbe[ND];
    __shared__ float sx[NS * NF];
    __shared__ float sWp[ND * NF];     // [d][f]
    __shared__ float sbp[NF];
    __shared__ float senc[NS * 65];    // stride-65 pad
    __shared__ float red[4];
    const int t = threadIdx.x, b = blockIdx.x;
    sW[t] = Wemb[t]; sW[t + 256] = Wemb[t + 256];
    sWp[t] = Wp[t];  sWp[t + 256] = Wp[t + 256];
    if (t < ND) sbe[t] = bemb[t];
    if (t < NF) sbp[t] = bp[t];
    sx[t] = x[(size_t)b * 512 + t];
    sx[t + 256] = x[(size_t)b * 512 + 256 + t];
    __syncthreads();
    const size_t rb = (size_t)b * NL;
    #pragma unroll
    for (int i = 0; i < 16; ++i) {
        const int idx = t + i * 256;
        const int s = idx >> 6, d = idx & 63;
        float a = sbe[d];
        #pragma unroll
        for (int f = 0; f < NF; ++f) a += sx[s * NF + f] * sW[f * ND + d];
        senc[s * 65 + d] = a;
        Af[rb + idx] = (_Float16)a;
    }
    __syncthreads();
    float s1 = 0.f;
    #pragma unroll
    for (int i = 0; i < 2; ++i) {
        const int e = t + i * 256;
        const int s = e >> 3, f = e & 7;
        float a = sbp[f];
        #pragma unroll
        for (int d = 0; d < ND; ++d) a += senc[s * 65 + d] * sWp[d * NF + f];
        proj[(size_t)b * 512 + e] = a;
        const float df = a - sx[e];
        s1 += df * df;
    }
    const float tot = blk_reduce(s1, red);
    if (t == 0) atomicAdd(&acc[0], (double)tot);
}

// ---- attn = X@X^T (unscaled, no diag mask) fp16 MFMA, lower-tri, dbuf pipeline ----
__global__ __launch_bounds__(256) void attn_gemm_kernel(
    const _Float16* __restrict__ Af, float* __restrict__ C)
{
    // [buf][A|B][128 rows][4 chunks of 8 halves]; 32 KB
    __shared__ __align__(16) _Float16 smem[4 * 4096];

    const int t = threadIdx.x;
    const int lane = t & 63, wid = t >> 6;
    const int wr = wid >> 1, wc = wid & 1;     // 2x2 waves, each 64x64 out

    // triangular block decode: bid -> (it, jt), jt <= it
    int bid = blockIdx.x;
    int it = (int)((sqrtf(8.0f * (float)bid + 1.0f) - 1.0f) * 0.5f);
    while ((it + 1) * (it + 2) / 2 <= bid) ++it;
    while (it * (it + 1) / 2 > bid) --it;
    const int jt = bid - it * (it + 1) / 2;
    const int i0 = it * 128, j0 = jt * 128;

    f32x4 acc[4][4];
    #pragma unroll
    for (int m = 0; m < 4; ++m)
        #pragma unroll
        for (int n = 0; n < 4; ++n) acc[m][n] = (f32x4){0.f, 0.f, 0.f, 0.f};

    // stage with source-side XOR swizzle: chunk' = cc ^ ((row>>1)&3)
#define STAGE(buf, kk)                                                     \
    {                                                                      \
        _Pragma("unroll")                                                  \
        for (int j = 0; j < 2; ++j) {                                      \
            const int c = t + j * 256;                                     \
            const int row = c >> 2;                                        \
            const int ccs = (c & 3) ^ ((row >> 1) & 3);                    \
            GLD16(Af + (size_t)(i0 + row) * NL + (kk) + ccs * 8,           \
                  smem + (buf) * 8192 + c * 8);                            \
            GLD16(Af + (size_t)(j0 + row) * NL + (kk) + ccs * 8,           \
                  smem + (buf) * 8192 + 4096 + c * 8);                     \
        }                                                                  \
    }

    const int lrow = lane & 15, g = lane >> 4;
    const int ksw = (g ^ ((lrow >> 1) & 3)) * 8;   // swizzled chunk on read side

    STAGE(0, 0);

    for (int k0 = 0; k0 < NL; k0 += 32) {
        const int cur = (k0 >> 5) & 1;
        asm volatile("s_waitcnt vmcnt(0)");
        __builtin_amdgcn_s_barrier();
        if (k0 + 32 < NL) STAGE(cur ^ 1, k0 + 32);

        const _Float16* sA = smem + cur * 8192;
        const _Float16* sB = sA + 4096;
        half8 fa[4], fb[4];
        #pragma unroll
        for (int m = 0; m < 4; ++m) {
            fa[m] = *(const half8*)&sA[(wr * 64 + m * 16 + lrow) * 32 + ksw];
            fb[m] = *(const half8*)&sB[(wc * 64 + m * 16 + lrow) * 32 + ksw];
        }
        #pragma unroll
        for (int m = 0; m < 4; ++m)
            #pragma unroll
            for (int n = 0; n < 4; ++n)
                acc[m][n] = __builtin_amdgcn_mfma_f32_16x16x32_f16(fa[m], fb[n], acc[m][n], 0, 0, 0);
    }
#undef STAGE

    // epilogue: C/D layout col=lane&15, row=(lane>>4)*4+reg
    const int diag = (it == jt);
    #pragma unroll
    for (int m = 0; m < 4; ++m)
        #pragma unroll
        for (int n = 0; n < 4; ++n)
            #pragma unroll
            for (int r = 0; r < 4; ++r) {
                const int i = i0 + wr * 64 + m * 16 + (lane >> 4) * 4 + r;
                const int j = j0 + wc * 64 + n * 16 + (lane & 15);
                const float v = acc[m][n][r];
                C[(size_t)i * NB + j] = v;
                if (!diag) C[(size_t)j * NB + i] = v;
            }
}

// ---------------- top-k: one wave per row, barrier-free chunk-cached argmax ----------------
__global__ __launch_bounds__(256) void topk_kernel(
    const float* __restrict__ attn, int* __restrict__ topidx)
{
    __shared__ float rows[4][NB];   // 64 KB
    const int t = threadIdx.x, lane = t & 63, w = t >> 6;
    const int b = blockIdx.x * 4 + w;
    float* srow = rows[w];
    const float4* src = (const float4*)(attn + (size_t)b * NB);
    #pragma unroll
    for (int j = 0; j < 16; ++j) {
        const int c4 = j * 64 + lane;
        *(float4*)&srow[c4 * 4] = src[c4];
    }
    __syncthreads();
    if (lane == (b & 63)) srow[b] = -INFINITY;   // mask self

    float cv[4]; int ci[4];
    #pragma unroll
    for (int q = 0; q < 4; ++q) {
        float bv = -INFINITY; int bi = 0;
        #pragma unroll
        for (int j = 0; j < 16; ++j) {
            const int e = (q * 16 + j) * 64 + lane;
            const float v = srow[e];
            if (v > bv) { bv = v; bi = e; }
        }
        cv[q] = bv; ci[q] = bi;
    }

    for (int k = 0; k < NK; ++k) {
        float bv = cv[0]; int bi = ci[0];
        #pragma unroll
        for (int q = 1; q < 4; ++q)
            if (cv[q] > bv || (cv[q] == bv && ci[q] < bi)) { bv = cv[q]; bi = ci[q]; }
        float v = bv; int idx = bi;
        #pragma unroll
        for (int o = 32; o > 0; o >>= 1) {
            const float v2 = __shfl_xor(v, o, 64);
            const int  i2 = __shfl_xor(idx, o, 64);
            if (v2 > v || (v2 == v && i2 < idx)) { v = v2; idx = i2; }
        }
        if (lane == 0) topidx[b * NK + k] = idx;
        if ((idx & 63) == lane) {
            srow[idx] = -INFINITY;
            const int q = idx >> 10;
            float nbv = -INFINITY; int nbi = 0;
            #pragma unroll
            for (int j = 0; j < 16; ++j) {
                const int e = (q * 16 + j) * 64 + lane;
                const float v3 = srow[e];
                if (v3 > nbv) { nbv = v3; nbi = e; }
            }
            cv[q] = nbv; ci[q] = nbi;
        }
    }
}

// ---------------- gathered diffs ----------------
__global__ __launch_bounds__(256) void diffs_kernel(
    const float* __restrict__ proj, const int* __restrict__ topidx, double* __restrict__ acc)
{
    __shared__ float g[NK][NS * NF];   // 32 KB
    __shared__ int sidx[NK];
    __shared__ float red[4];
    const int t = threadIdx.x, b = blockIdx.x;
    if (t < NK) sidx[t] = topidx[b * NK + t];
    __syncthreads();
    for (int q = t; q < NK * 512; q += 256) {
        const int kk = q >> 9, e = q & 511;
        g[kk][e] = proj[(size_t)sidx[kk] * 512 + e];
    }
    __syncthreads();
    float s1 = 0.f, s2 = 0.f;
    for (int q = t; q < 15 * 512; q += 256) {
        const int kk = q >> 9, e = q & 511;
        const float d = g[kk + 1][e] - g[kk][e];
        s1 += d * d;
    }
    for (int q = t; q < 16 * 504; q += 256) {
        const int kk = q / 504, e = q % 504;
        const float d = g[kk][e + 8] - g[kk][e];
        s2 += d * d;
    }
    const float t1 = blk_reduce(s1, red);
    if (threadIdx.x == 0) atomicAdd(&acc[1], (double)t1);
    __syncthreads();
    const float t2 = blk_reduce(s2, red);
    if (threadIdx.x == 0) atomicAdd(&acc[2], (double)t2);
}

// ---------------- finalize loss ----------------
__global__ void finalize_kernel(const double* __restrict__ acc, float* __restrict__ out) {
    if (threadIdx.x == 0) {
        const double loss = acc[0] / 2097152.0      // B*S*F
                          + acc[1] / 31457280.0     // B*(K-1)*S*F
                          + acc[2] / 33030144.0;    // B*K*(S-1)*F
        out[0] = (float)loss;
    }
}

extern "C" void kernel_launch(void* const* d_in, const int* in_sizes, int n_in,
                              void* d_out, int out_size, void* d_ws, size_t ws_size,
                              hipStream_t stream) {
    const float* x    = (const float*)d_in[0];
    const float* Wemb = (const float*)d_in[1];
    const float* bemb = (const float*)d_in[2];
    const float* Wp   = (const float*)d_in[3];
    const float* bp   = (const float*)d_in[4];
    float* out  = (float*)d_out;
    float* proj = out + 1;                       // x_rec_proj, B*S*F floats

    char* ws = (char*)d_ws;
    _Float16* Af   = (_Float16*)ws;                            // 32 MB
    float*  attn   = (float*)(ws + ((size_t)32 << 20));        // 64 MB
    int*    topidx = (int*)  (ws + ((size_t)96 << 20));        // 256 KB
    double* acc    = (double*)(ws + ((size_t)97 << 20));       // 64 B

    init_acc_kernel<<<1, 64, 0, stream>>>(acc);
    embed_proj_kernel<<<NB, 256, 0, stream>>>(x, Wemb, bemb, Wp, bp, Af, proj, acc);
    attn_gemm_kernel<<<(32 * 33) / 2, 256, 0, stream>>>(Af, attn);
    topk_kernel<<<NB / 4, 256, 0, stream>>>(attn, topidx);
    diffs_kernel<<<NB, 256, 0, stream>>>(proj, topidx, acc);
    finalize_kernel<<<1, 64, 0, stream>>>(acc, out);
}

// Round 5
// 227.152 us; speedup vs baseline: 10.3460x; 1.6269x over previous
//
#include <hip/hip_runtime.h>
#include <math.h>

#define NB 4096   // batch
#define NS 64     // seq
#define NF 8      // feat
#define ND 64     // d_model
#define NL 4096   // NS*ND
#define NK 16     // top-k

typedef _Float16 half8 __attribute__((ext_vector_type(8)));
typedef float    f32x4 __attribute__((ext_vector_type(4)));

#define GLD16(src, dst) \
  __builtin_amdgcn_global_load_lds((const __attribute__((address_space(1))) void*)(src), \
                                   (__attribute__((address_space(3))) void*)(dst), 16, 0, 0)

#define WAITVM(N) asm volatile("s_waitcnt vmcnt(" #N ")" ::: "memory")

// ---------------- block reduce helper ----------------
__device__ __forceinline__ float blk_reduce(float v, float* red) {
    #pragma unroll
    for (int o = 32; o > 0; o >>= 1) v += __shfl_down(v, o, 64);
    const int t = threadIdx.x;
    __syncthreads();
    if ((t & 63) == 0) red[t >> 6] = v;
    __syncthreads();
    float r = 0.f;
    if (t == 0) r = red[0] + red[1] + red[2] + red[3];
    return r;
}

// ---- fused: x_enc = x@Wemb+b (fp16 store) ; proj = x_enc@Wp+bp ; term1 ----
__global__ __launch_bounds__(256) void embed_proj_kernel(
    const float* __restrict__ x, const float* __restrict__ Wemb,
    const float* __restrict__ bemb, const float* __restrict__ Wp,
    const float* __restrict__ bp,
    _Float16* __restrict__ Af, float* __restrict__ proj, double* __restrict__ acc)
{
    __shared__ float sW[NF * ND];      // [f][d]
    __shared__ float sbe[ND];
    __shared__ float sx[NS * NF];
    __shared__ float sWp[ND * NF];     // [d][f]
    __shared__ float sbp[NF];
    __shared__ float senc[NS * 65];    // stride-65 pad
    __shared__ float red[4];
    const int t = threadIdx.x, b = blockIdx.x;
    sW[t] = Wemb[t]; sW[t + 256] = Wemb[t + 256];
    sWp[t] = Wp[t];  sWp[t + 256] = Wp[t + 256];
    if (t < ND) sbe[t] = bemb[t];
    if (t < NF) sbp[t] = bp[t];
    sx[t] = x[(size_t)b * 512 + t];
    sx[t + 256] = x[(size_t)b * 512 + 256 + t];
    __syncthreads();
    const size_t rb = (size_t)b * NL;
    #pragma unroll
    for (int i = 0; i < 16; ++i) {
        const int idx = t + i * 256;
        const int s = idx >> 6, d = idx & 63;
        float a = sbe[d];
        #pragma unroll
        for (int f = 0; f < NF; ++f) a += sx[s * NF + f] * sW[f * ND + d];
        senc[s * 65 + d] = a;
        Af[rb + idx] = (_Float16)a;
    }
    __syncthreads();
    float s1 = 0.f;
    #pragma unroll
    for (int i = 0; i < 2; ++i) {
        const int e = t + i * 256;
        const int s = e >> 3, f = e & 7;
        float a = sbp[f];
        #pragma unroll
        for (int d = 0; d < ND; ++d) a += senc[s * 65 + d] * sWp[d * NF + f];
        proj[(size_t)b * 512 + e] = a;
        const float df = a - sx[e];
        s1 += df * df;
    }
    const float tot = blk_reduce(s1, red);
    if (t == 0) atomicAdd(&acc[(size_t)(blockIdx.x & 31) * 8], (double)tot);
}

// ---- attn = X@X^T fp16 MFMA, lower-tri, depth-3 counted-vmcnt pipeline ----
__global__ __launch_bounds__(256) void attn_gemm_kernel(
    const _Float16* __restrict__ Af, float* __restrict__ C)
{
    // 4 bufs x (A 4096 + B 4096 halves) = 64 KB; reused as 128x128 f32 for transpose
    __shared__ __align__(16) char smem_raw[65536];
    _Float16* smem = (_Float16*)smem_raw;

    const int t = threadIdx.x;
    const int lane = t & 63, wid = t >> 6;
    const int wr = wid >> 1, wc = wid & 1;     // 2x2 waves, each 64x64 out

    // XCD-chunked swizzle: 528 = 8 x 66
    const int bid0 = blockIdx.x;
    const int bid = (bid0 & 7) * 66 + (bid0 >> 3);

    // triangular block decode: bid -> (it, jt), jt <= it
    int it = (int)((sqrtf(8.0f * (float)bid + 1.0f) - 1.0f) * 0.5f);
    while ((it + 1) * (it + 2) / 2 <= bid) ++it;
    while (it * (it + 1) / 2 > bid) --it;
    const int jt = bid - it * (it + 1) / 2;
    const int i0 = it * 128, j0 = jt * 128;

    f32x4 acc[4][4];
    #pragma unroll
    for (int m = 0; m < 4; ++m)
        #pragma unroll
        for (int n = 0; n < 4; ++n) acc[m][n] = (f32x4){0.f, 0.f, 0.f, 0.f};

    const int lrow = lane & 15, g = lane >> 4;
    const int ksw = (g ^ ((lrow >> 1) & 3)) * 8;   // read-side chunk swizzle

    auto stage = [&](int si) {
        if (si < 128) {
            const int kk = si * 32;
            _Float16* dst = smem + (si & 3) * 8192;
            #pragma unroll
            for (int j = 0; j < 2; ++j) {
                const int c = t + j * 256;
                const int row = c >> 2;
                const int ccs = (c & 3) ^ ((row >> 1) & 3);   // source-side swizzle
                GLD16(Af + (size_t)(i0 + row) * NL + kk + ccs * 8, dst + c * 8);
                GLD16(Af + (size_t)(j0 + row) * NL + kk + ccs * 8, dst + 4096 + c * 8);
            }
        }
    };
    auto compute = [&](int bufi) {
        const _Float16* sA = smem + bufi * 8192;
        const _Float16* sB = sA + 4096;
        half8 fa[4], fb[4];
        #pragma unroll
        for (int m = 0; m < 4; ++m) {
            fa[m] = *(const half8*)&sA[(wr * 64 + m * 16 + lrow) * 32 + ksw];
            fb[m] = *(const half8*)&sB[(wc * 64 + m * 16 + lrow) * 32 + ksw];
        }
        #pragma unroll
        for (int m = 0; m < 4; ++m)
            #pragma unroll
            for (int n = 0; n < 4; ++n)
                acc[m][n] = __builtin_amdgcn_mfma_f32_16x16x32_f16(fa[m], fb[n], acc[m][n], 0, 0, 0);
    };

    stage(0); stage(1); stage(2);
    for (int i = 0; i < 126; ++i) {
        WAITVM(8);                          // oldest stage (buf i) complete
        __builtin_amdgcn_s_barrier();
        stage(i + 3);
        compute(i & 3);
    }
    WAITVM(4); __builtin_amdgcn_s_barrier(); compute(2);   // i = 126
    WAITVM(0); __builtin_amdgcn_s_barrier(); compute(3);   // i = 127

    // direct store (i-major), quarter-wave 64B segments
    const int diag = (it == jt);
    #pragma unroll
    for (int m = 0; m < 4; ++m)
        #pragma unroll
        for (int n = 0; n < 4; ++n)
            #pragma unroll
            for (int r = 0; r < 4; ++r) {
                const int i = i0 + wr * 64 + m * 16 + g * 4 + r;
                const int j = j0 + wc * 64 + n * 16 + lrow;
                C[(size_t)i * NB + j] = acc[m][n][r];
            }

    // mirror store via LDS transpose (coalesced)
    if (!diag) {
        __syncthreads();
        float* fsm = (float*)smem_raw;     // [128][128] w/ XOR swizzle
        #pragma unroll
        for (int m = 0; m < 4; ++m)
            #pragma unroll
            for (int n = 0; n < 4; ++n) {
                const int jloc = wc * 64 + n * 16 + lrow;
                const int ilocb = wr * 64 + m * 16 + g * 4;
                *(f32x4*)&fsm[jloc * 128 + (ilocb ^ ((jloc & 7) << 2))] = acc[m][n];
            }
        __syncthreads();
        #pragma unroll
        for (int rep = 0; rep < 16; ++rep) {
            const int idx = rep * 1024 + t * 4;
            const int jloc = idx >> 7, iloc = idx & 127;
            const f32x4 v = *(const f32x4*)&fsm[jloc * 128 + (iloc ^ ((jloc & 7) << 2))];
            *(f32x4*)&C[(size_t)(j0 + jloc) * NB + i0 + iloc] = v;
        }
    }
}

// ---------------- fused top-k + gathered diffs: one wave per row ----------------
__global__ __launch_bounds__(256) void topk_diffs_kernel(
    const float* __restrict__ attn, const float* __restrict__ proj, double* __restrict__ acc)
{
    __shared__ float rows[4][NB];   // 64 KB
    __shared__ int sidx[4][NK];
    const int t = threadIdx.x, lane = t & 63, w = t >> 6;
    const int b = blockIdx.x * 4 + w;
    float* srow = rows[w];
    const float4* src = (const float4*)(attn + (size_t)b * NB);
    #pragma unroll
    for (int j = 0; j < 16; ++j) {
        const int c4 = j * 64 + lane;
        *(float4*)&srow[c4 * 4] = src[c4];
    }
    if (lane == (b & 63)) srow[b] = -INFINITY;   // mask self (owner lane)

    // per-lane chunk caches: lane owns e with e%64==lane; 4 chunks of 16
    float cv[4]; int ci[4];
    #pragma unroll
    for (int q = 0; q < 4; ++q) {
        float bv = -INFINITY; int bi = 0;
        #pragma unroll
        for (int j = 0; j < 16; ++j) {
            const int e = (q * 16 + j) * 64 + lane;
            const float v = srow[e];
            if (v > bv) { bv = v; bi = e; }
        }
        cv[q] = bv; ci[q] = bi;
    }

    for (int k = 0; k < NK; ++k) {
        float bv = cv[0]; int bi = ci[0];
        #pragma unroll
        for (int q = 1; q < 4; ++q)
            if (cv[q] > bv || (cv[q] == bv && ci[q] < bi)) { bv = cv[q]; bi = ci[q]; }
        float v = bv; int idx = bi;
        #pragma unroll
        for (int o = 32; o > 0; o >>= 1) {
            const float v2 = __shfl_xor(v, o, 64);
            const int  i2 = __shfl_xor(idx, o, 64);
            if (v2 > v || (v2 == v && i2 < idx)) { v = v2; idx = i2; }
        }
        if (lane == 0) sidx[w][k] = idx;
        if ((idx & 63) == lane) {                 // owner invalidates + rescans chunk
            srow[idx] = -INFINITY;
            const int q = idx >> 10;
            float nbv = -INFINITY; int nbi = 0;
            #pragma unroll
            for (int j = 0; j < 16; ++j) {
                const int e = (q * 16 + j) * 64 + lane;
                const float v3 = srow[e];
                if (v3 > nbv) { nbv = v3; nbi = e; }
            }
            cv[q] = nbv; ci[q] = nbi;
        }
    }

    // diffs: stream 16 gathered proj rows; lane holds 8 consecutive floats
    float s1 = 0.f, s2 = 0.f;
    float prev[8];
    for (int k = 0; k < NK; ++k) {
        const float4* p = (const float4*)(proj + (size_t)sidx[w][k] * 512 + lane * 8);
        const float4 a0 = p[0], a1 = p[1];
        float cur[8] = {a0.x, a0.y, a0.z, a0.w, a1.x, a1.y, a1.z, a1.w};
        if (k) {
            #pragma unroll
            for (int j = 0; j < 8; ++j) { const float d = cur[j] - prev[j]; s1 += d * d; }
        }
        #pragma unroll
        for (int j = 0; j < 8; ++j) {
            const float nb = __shfl_down(cur[j], 1, 64);
            if (lane < 63) { const float d = nb - cur[j]; s2 += d * d; }
        }
        #pragma unroll
        for (int j = 0; j < 8; ++j) prev[j] = cur[j];
    }
    #pragma unroll
    for (int o = 32; o > 0; o >>= 1) { s1 += __shfl_down(s1, o, 64); s2 += __shfl_down(s2, o, 64); }
    if (lane == 0) {
        const size_t slot = (size_t)(blockIdx.x & 31) * 8;
        atomicAdd(&acc[(size_t)32 * 8 + slot], (double)s1);
        atomicAdd(&acc[(size_t)64 * 8 + slot], (double)s2);
    }
}

// ---------------- finalize loss ----------------
__global__ void finalize_kernel(const double* __restrict__ acc, float* __restrict__ out) {
    if (threadIdx.x == 0) {
        double s0 = 0.0, s1 = 0.0, s2 = 0.0;
        #pragma unroll
        for (int i = 0; i < 32; ++i) {
            s0 += acc[(size_t)i * 8];
            s1 += acc[(size_t)(32 + i) * 8];
            s2 += acc[(size_t)(64 + i) * 8];
        }
        out[0] = (float)(s0 / 2097152.0 + s1 / 31457280.0 + s2 / 33030144.0);
    }
}

extern "C" void kernel_launch(void* const* d_in, const int* in_sizes, int n_in,
                              void* d_out, int out_size, void* d_ws, size_t ws_size,
                              hipStream_t stream) {
    const float* x    = (const float*)d_in[0];
    const float* Wemb = (const float*)d_in[1];
    const float* bemb = (const float*)d_in[2];
    const float* Wp   = (const float*)d_in[3];
    const float* bp   = (const float*)d_in[4];
    float* out  = (float*)d_out;
    float* proj = out + 1;                       // x_rec_proj, B*S*F floats

    char* ws = (char*)d_ws;
    _Float16* Af   = (_Float16*)ws;                            // 32 MB
    float*  attn   = (float*)(ws + ((size_t)32 << 20));        // 64 MB
    double* acc    = (double*)(ws + ((size_t)96 << 20));       // 96 slots x 64B stride

    hipMemsetAsync(acc, 0, 96 * 8 * sizeof(double), stream);
    embed_proj_kernel<<<NB, 256, 0, stream>>>(x, Wemb, bemb, Wp, bp, Af, proj, acc);
    attn_gemm_kernel<<<(32 * 33) / 2, 256, 0, stream>>>(Af, attn);
    topk_diffs_kernel<<<NB / 4, 256, 0, stream>>>(attn, proj, acc);
    finalize_kernel<<<1, 64, 0, stream>>>(acc, out);
}

// Round 6
// 208.188 us; speedup vs baseline: 11.2885x; 1.0911x over previous
//
#include <hip/hip_runtime.h>
#include <math.h>

#define NB 4096   // batch
#define NS 64     // seq
#define NF 8      // feat
#define ND 64     // d_model
#define NL 4096   // NS*ND
#define NK 16     // top-k

typedef _Float16 half8 __attribute__((ext_vector_type(8)));
typedef float    f32x4 __attribute__((ext_vector_type(4)));

#define GLD16(src, dst) \
  __builtin_amdgcn_global_load_lds((const __attribute__((address_space(1))) void*)(src), \
                                   (__attribute__((address_space(3))) void*)(dst), 16, 0, 0)

#define WAITVM(N) asm volatile("s_waitcnt vmcnt(" #N ")" ::: "memory")

// ---------------- block reduce helper ----------------
__device__ __forceinline__ float blk_reduce(float v, float* red) {
    #pragma unroll
    for (int o = 32; o > 0; o >>= 1) v += __shfl_down(v, o, 64);
    const int t = threadIdx.x;
    __syncthreads();
    if ((t & 63) == 0) red[t >> 6] = v;
    __syncthreads();
    float r = 0.f;
    if (t == 0) r = red[0] + red[1] + red[2] + red[3];
    return r;
}

// ---- fused: x_enc = x@Wemb+b (fp16 store) ; proj = x_enc@Wp+bp ; term1 ----
__global__ __launch_bounds__(256) void embed_proj_kernel(
    const float* __restrict__ x, const float* __restrict__ Wemb,
    const float* __restrict__ bemb, const float* __restrict__ Wp,
    const float* __restrict__ bp,
    _Float16* __restrict__ Af, float* __restrict__ proj, double* __restrict__ acc)
{
    __shared__ float sW[NF * ND];      // [f][d]
    __shared__ float sbe[ND];
    __shared__ float sx[NS * NF];
    __shared__ float sWp[ND * NF];     // [d][f]
    __shared__ float sbp[NF];
    __shared__ float senc[NS * 65];    // stride-65 pad
    __shared__ float red[4];
    const int t = threadIdx.x, b = blockIdx.x;
    sW[t] = Wemb[t]; sW[t + 256] = Wemb[t + 256];
    sWp[t] = Wp[t];  sWp[t + 256] = Wp[t + 256];
    if (t < ND) sbe[t] = bemb[t];
    if (t < NF) sbp[t] = bp[t];
    sx[t] = x[(size_t)b * 512 + t];
    sx[t + 256] = x[(size_t)b * 512 + 256 + t];
    __syncthreads();
    const size_t rb = (size_t)b * NL;
    #pragma unroll
    for (int i = 0; i < 16; ++i) {
        const int idx = t + i * 256;
        const int s = idx >> 6, d = idx & 63;
        float a = sbe[d];
        #pragma unroll
        for (int f = 0; f < NF; ++f) a += sx[s * NF + f] * sW[f * ND + d];
        senc[s * 65 + d] = a;
        Af[rb + idx] = (_Float16)a;
    }
    __syncthreads();
    float s1 = 0.f;
    #pragma unroll
    for (int i = 0; i < 2; ++i) {
        const int e = t + i * 256;
        const int s = e >> 3, f = e & 7;
        float a = sbp[f];
        #pragma unroll
        for (int d = 0; d < ND; ++d) a += senc[s * 65 + d] * sWp[d * NF + f];
        proj[(size_t)b * 512 + e] = a;
        const float df = a - sx[e];
        s1 += df * df;
    }
    const float tot = blk_reduce(s1, red);
    if (t == 0) atomicAdd(&acc[(size_t)(blockIdx.x & 31) * 8], (double)tot);
}

// ---- attn = X@X^T fp16 MFMA, lower-tri, depth-3 pipeline, hoisted addresses ----
__global__ __launch_bounds__(256) void attn_gemm_kernel(
    const _Float16* __restrict__ Af, float* __restrict__ C)
{
    // 4 bufs x (A 4096 + B 4096 halves) = 64 KB; reused as 128x128 f32 for transpose
    __shared__ __align__(16) char smem_raw[65536];
    _Float16* smem = (_Float16*)smem_raw;

    const int t = threadIdx.x;
    const int lane = t & 63, wid = t >> 6;
    const int wr = wid >> 1, wc = wid & 1;     // 2x2 waves, each 64x64 out

    // XCD-chunked swizzle: 528 = 8 x 66
    const int bid0 = blockIdx.x;
    const int bid = (bid0 & 7) * 66 + (bid0 >> 3);

    // triangular block decode: bid -> (it, jt), jt <= it
    int it = (int)((sqrtf(8.0f * (float)bid + 1.0f) - 1.0f) * 0.5f);
    while ((it + 1) * (it + 2) / 2 <= bid) ++it;
    while (it * (it + 1) / 2 > bid) --it;
    const int jt = bid - it * (it + 1) / 2;
    const int i0 = it * 128, j0 = jt * 128;

    f32x4 acc[4][4];
    #pragma unroll
    for (int m = 0; m < 4; ++m)
        #pragma unroll
        for (int n = 0; n < 4; ++n) acc[m][n] = (f32x4){0.f, 0.f, 0.f, 0.f};

    const int lrow = lane & 15, g = lane >> 4;
    const int ksw = (g ^ ((lrow >> 1) & 3)) * 8;   // read-side chunk swizzle

    // hoisted per-thread staging addresses (source-side swizzle folded in)
    const int c0 = t, c1 = t + 256;
    const int r0 = c0 >> 2, r1 = c1 >> 2;
    const int cs0 = ((c0 & 3) ^ ((r0 >> 1) & 3)) * 8;
    const int cs1 = ((c1 & 3) ^ ((r1 >> 1) & 3)) * 8;
    const _Float16* pa0 = Af + (size_t)(i0 + r0) * NL + cs0;
    const _Float16* pa1 = Af + (size_t)(i0 + r1) * NL + cs1;
    const _Float16* pb0 = Af + (size_t)(j0 + r0) * NL + cs0;
    const _Float16* pb1 = Af + (size_t)(j0 + r1) * NL + cs1;
    _Float16* d0 = smem + c0 * 8;      // buf-0 LDS slots for this thread
    _Float16* d1 = smem + c1 * 8;

    // BUF and KH are compile-time literals at every call site
#define STG(BUF, KH) { \
    GLD16(pa0 + (KH), d0 + (BUF) * 8192); \
    GLD16(pa1 + (KH), d1 + (BUF) * 8192); \
    GLD16(pb0 + (KH), d0 + (BUF) * 8192 + 4096); \
    GLD16(pb1 + (KH), d1 + (BUF) * 8192 + 4096); }

    const int roA = wr * 2048 + lrow * 32 + ksw;
    const int roB = wc * 2048 + lrow * 32 + ksw;

#define COMPUTE(BUF) { \
    const _Float16* sA = smem + (BUF) * 8192; \
    const _Float16* sB = sA + 4096; \
    half8 fa[4], fb[4]; \
    _Pragma("unroll") \
    for (int m = 0; m < 4; ++m) { \
        fa[m] = *(const half8*)&sA[roA + m * 512]; \
        fb[m] = *(const half8*)&sB[roB + m * 512]; \
    } \
    __builtin_amdgcn_s_setprio(1); \
    _Pragma("unroll") \
    for (int m = 0; m < 4; ++m) \
        _Pragma("unroll") \
        for (int n = 0; n < 4; ++n) \
            acc[m][n] = __builtin_amdgcn_mfma_f32_16x16x32_f16(fa[m], fb[n], acc[m][n], 0, 0, 0); \
    __builtin_amdgcn_s_setprio(0); }

    // prologue: stages 0,1,2 (K-offsets 0,32,64 halves)
    STG(0, 0); STG(1, 32); STG(2, 64);
    pa0 += 96; pa1 += 96; pb0 += 96; pb1 += 96;   // -> stage-3 base

    // steady state: i = 0..119 (stages 3..122), unroll 4 => all indices literal
    #pragma unroll 1
    for (int io = 0; io < 30; ++io) {
        WAITVM(8); __builtin_amdgcn_s_barrier(); STG(3, 0);  COMPUTE(0);
        WAITVM(8); __builtin_amdgcn_s_barrier(); STG(0, 32); COMPUTE(1);
        WAITVM(8); __builtin_amdgcn_s_barrier(); STG(1, 64); COMPUTE(2);
        WAITVM(8); __builtin_amdgcn_s_barrier(); STG(2, 96); COMPUTE(3);
        pa0 += 128; pa1 += 128; pb0 += 128; pb1 += 128;
    }
    // tail: i = 120..127 (stages 123..127 from stage-123 base)
    WAITVM(8); __builtin_amdgcn_s_barrier(); STG(3, 0);   COMPUTE(0);
    WAITVM(8); __builtin_amdgcn_s_barrier(); STG(0, 32);  COMPUTE(1);
    WAITVM(8); __builtin_amdgcn_s_barrier(); STG(1, 64);  COMPUTE(2);
    WAITVM(8); __builtin_amdgcn_s_barrier(); STG(2, 96);  COMPUTE(3);
    WAITVM(8); __builtin_amdgcn_s_barrier(); STG(3, 128); COMPUTE(0);
    WAITVM(8); __builtin_amdgcn_s_barrier(); COMPUTE(1);
    WAITVM(4); __builtin_amdgcn_s_barrier(); COMPUTE(2);
    WAITVM(0); __builtin_amdgcn_s_barrier(); COMPUTE(3);
#undef STG
#undef COMPUTE

    // direct store (i-major), quarter-wave 64B segments
    const int diag = (it == jt);
    #pragma unroll
    for (int m = 0; m < 4; ++m)
        #pragma unroll
        for (int n = 0; n < 4; ++n)
            #pragma unroll
            for (int r = 0; r < 4; ++r) {
                const int i = i0 + wr * 64 + m * 16 + g * 4 + r;
                const int j = j0 + wc * 64 + n * 16 + lrow;
                C[(size_t)i * NB + j] = acc[m][n][r];
            }

    // mirror store via LDS transpose (coalesced)
    if (!diag) {
        __syncthreads();
        float* fsm = (float*)smem_raw;     // [128][128] w/ XOR swizzle
        #pragma unroll
        for (int m = 0; m < 4; ++m)
            #pragma unroll
            for (int n = 0; n < 4; ++n) {
                const int jloc = wc * 64 + n * 16 + lrow;
                const int ilocb = wr * 64 + m * 16 + g * 4;
                *(f32x4*)&fsm[jloc * 128 + (ilocb ^ ((jloc & 7) << 2))] = acc[m][n];
            }
        __syncthreads();
        #pragma unroll
        for (int rep = 0; rep < 16; ++rep) {
            const int idx = rep * 1024 + t * 4;
            const int jloc = idx >> 7, iloc = idx & 127;
            const f32x4 v = *(const f32x4*)&fsm[jloc * 128 + (iloc ^ ((jloc & 7) << 2))];
            *(f32x4*)&C[(size_t)(j0 + jloc) * NB + i0 + iloc] = v;
        }
    }
}

// ---------------- fused top-k + gathered diffs: one wave per row ----------------
__global__ __launch_bounds__(256) void topk_diffs_kernel(
    const float* __restrict__ attn, const float* __restrict__ proj, double* __restrict__ acc)
{
    __shared__ float rows[4][NB];   // 64 KB
    __shared__ int sidx[4][NK];
    const int t = threadIdx.x, lane = t & 63, w = t >> 6;
    const int b = blockIdx.x * 4 + w;
    float* srow = rows[w];
    const float4* src = (const float4*)(attn + (size_t)b * NB);
    #pragma unroll
    for (int j = 0; j < 16; ++j) {
        const int c4 = j * 64 + lane;
        *(float4*)&srow[c4 * 4] = src[c4];
    }
    if (lane == (b & 63)) srow[b] = -INFINITY;   // mask self (owner lane)

    // per-lane chunk caches: lane owns e with e%64==lane; 4 chunks of 16
    float cv[4]; int ci[4];
    #pragma unroll
    for (int q = 0; q < 4; ++q) {
        float bv = -INFINITY; int bi = 0;
        #pragma unroll
        for (int j = 0; j < 16; ++j) {
            const int e = (q * 16 + j) * 64 + lane;
            const float v = srow[e];
            if (v > bv) { bv = v; bi = e; }
        }
        cv[q] = bv; ci[q] = bi;
    }

    for (int k = 0; k < NK; ++k) {
        float bv = cv[0]; int bi = ci[0];
        #pragma unroll
        for (int q = 1; q < 4; ++q)
            if (cv[q] > bv || (cv[q] == bv && ci[q] < bi)) { bv = cv[q]; bi = ci[q]; }
        float v = bv; int idx = bi;
        #pragma unroll
        for (int o = 32; o > 0; o >>= 1) {
            const float v2 = __shfl_xor(v, o, 64);
            const int  i2 = __shfl_xor(idx, o, 64);
            if (v2 > v || (v2 == v && i2 < idx)) { v = v2; idx = i2; }
        }
        if (lane == 0) sidx[w][k] = idx;
        if ((idx & 63) == lane) {                 // owner invalidates + rescans chunk
            srow[idx] = -INFINITY;
            const int q = idx >> 10;
            float nbv = -INFINITY; int nbi = 0;
            #pragma unroll
            for (int j = 0; j < 16; ++j) {
                const int e = (q * 16 + j) * 64 + lane;
                const float v3 = srow[e];
                if (v3 > nbv) { nbv = v3; nbi = e; }
            }
            cv[q] = nbv; ci[q] = nbi;
        }
    }

    // diffs: stream 16 gathered proj rows; lane holds 8 consecutive floats
    float s1 = 0.f, s2 = 0.f;
    float prev[8];
    for (int k = 0; k < NK; ++k) {
        const float4* p = (const float4*)(proj + (size_t)sidx[w][k] * 512 + lane * 8);
        const float4 a0 = p[0], a1 = p[1];
        float cur[8] = {a0.x, a0.y, a0.z, a0.w, a1.x, a1.y, a1.z, a1.w};
        if (k) {
            #pragma unroll
            for (int j = 0; j < 8; ++j) { const float d = cur[j] - prev[j]; s1 += d * d; }
        }
        #pragma unroll
        for (int j = 0; j < 8; ++j) {
            const float nb = __shfl_down(cur[j], 1, 64);
            if (lane < 63) { const float d = nb - cur[j]; s2 += d * d; }
        }
        #pragma unroll
        for (int j = 0; j < 8; ++j) prev[j] = cur[j];
    }
    #pragma unroll
    for (int o = 32; o > 0; o >>= 1) { s1 += __shfl_down(s1, o, 64); s2 += __shfl_down(s2, o, 64); }
    if (lane == 0) {
        const size_t slot = (size_t)(blockIdx.x & 31) * 8;
        atomicAdd(&acc[(size_t)32 * 8 + slot], (double)s1);
        atomicAdd(&acc[(size_t)64 * 8 + slot], (double)s2);
    }
}

// ---------------- finalize loss ----------------
__global__ void finalize_kernel(const double* __restrict__ acc, float* __restrict__ out) {
    if (threadIdx.x == 0) {
        double s0 = 0.0, s1 = 0.0, s2 = 0.0;
        #pragma unroll
        for (int i = 0; i < 32; ++i) {
            s0 += acc[(size_t)i * 8];
            s1 += acc[(size_t)(32 + i) * 8];
            s2 += acc[(size_t)(64 + i) * 8];
        }
        out[0] = (float)(s0 / 2097152.0 + s1 / 31457280.0 + s2 / 33030144.0);
    }
}

extern "C" void kernel_launch(void* const* d_in, const int* in_sizes, int n_in,
                              void* d_out, int out_size, void* d_ws, size_t ws_size,
                              hipStream_t stream) {
    const float* x    = (const float*)d_in[0];
    const float* Wemb = (const float*)d_in[1];
    const float* bemb = (const float*)d_in[2];
    const float* Wp   = (const float*)d_in[3];
    const float* bp   = (const float*)d_in[4];
    float* out  = (float*)d_out;
    float* proj = out + 1;                       // x_rec_proj, B*S*F floats

    char* ws = (char*)d_ws;
    _Float16* Af   = (_Float16*)ws;                            // 32 MB
    float*  attn   = (float*)(ws + ((size_t)32 << 20));        // 64 MB
    double* acc    = (double*)(ws + ((size_t)96 << 20));       // 96 slots x 64B stride

    hipMemsetAsync(acc, 0, 96 * 8 * sizeof(double), stream);
    embed_proj_kernel<<<NB, 256, 0, stream>>>(x, Wemb, bemb, Wp, bp, Af, proj, acc);
    attn_gemm_kernel<<<(32 * 33) / 2, 256, 0, stream>>>(Af, attn);
    topk_diffs_kernel<<<NB / 4, 256, 0, stream>>>(attn, proj, acc);
    finalize_kernel<<<1, 64, 0, stream>>>(acc, out);
}